// Round 11
// baseline (187.414 us; speedup 1.0000x reference)
//
#include <hip/hip_runtime.h>
#include <hip/hip_bf16.h>
#include <cstdint>

#define B_SZ   512
#define NLAT   64
#define H_SZ   32
#define G_OI_N 5000
#define K_SZ   64

#define GPC    20     // genes per chunk (250 chunks)
#define NCHUNK 250
#define KPAD   68     // padded k-dim (floats) in LDS epilogue tile

typedef __attribute__((ext_vector_type(8))) short short8v;   // 8 x bf16
typedef __attribute__((ext_vector_type(4))) float float4v;

__device__ __forceinline__ unsigned short f2bf(float x) {
    union { float f; unsigned u; } v; v.f = x;
    unsigned r = v.u + 0x7fff + ((v.u >> 16) & 1);            // RTNE
    return (unsigned short)(r >> 16);
}

// ---------------- Kernel A: h = BN(relu(latent @ W1 + b1))
__global__ __launch_bounds__(256) void mlp_kernel(
    const float* __restrict__ latent, const float* __restrict__ W1,
    const float* __restrict__ b1, const float* __restrict__ gamma,
    const float* __restrict__ beta, const float* __restrict__ mean,
    const float* __restrict__ var, float* __restrict__ hout,
    unsigned short* __restrict__ hbf)
{
    int idx = blockIdx.x * 256 + threadIdx.x;   // 0..16383 = b*32 + j
    int b = idx >> 5;
    int j = idx & 31;
    float acc = 0.f;
    const float4* lp = reinterpret_cast<const float4*>(latent + b * NLAT);
#pragma unroll
    for (int q = 0; q < NLAT / 4; ++q) {
        float4 lv = lp[q];
        acc = fmaf(lv.x, W1[(4 * q + 0) * H_SZ + j], acc);
        acc = fmaf(lv.y, W1[(4 * q + 1) * H_SZ + j], acc);
        acc = fmaf(lv.z, W1[(4 * q + 2) * H_SZ + j], acc);
        acc = fmaf(lv.w, W1[(4 * q + 3) * H_SZ + j], acc);
    }
    acc += b1[j];
    acc = fmaxf(acc, 0.f);
    acc = gamma[j] * (acc - mean[j]) * rsqrtf(var[j] + 1e-5f) + beta[j];
    hout[idx] = acc;
    hbf[idx]  = f2bf(acc);
}

// ---------------- Kernel B v4 (MFMA + LDS-staged fill-pattern epilogue):
// Block = 4 waves (wave = k-tile) x 128 b-rows (quarter) x 20 genes.
// Compute identical to HW-verified r10 mapping. Epilogue: per 16-row m-tile,
// D fragments -> LDS (k padded to 68 floats; write conflicts <=4-way, reads
// 2-way) -> barrier -> 256 threads stream out contiguous: 1 KB/wave-instr,
// 2.5 KB sequential per row per half (5 KB per mt) -> fill-kernel-like DRAM
// streams. lw read ~once (4 b-quarter blocks of a chunk are grid-adjacent).
__global__ __launch_bounds__(256) void logit_kernel(
    const unsigned short* __restrict__ hbf, const int* __restrict__ genes,
    const float* __restrict__ lw, float* __restrict__ out)
{
    __shared__ float lt[16 * 10 * KPAD];       // 43520 B
    const int bq    = blockIdx.x & 3;          // 128-row quarter
    const int chunk = blockIdx.x >> 2;         // 0..249
    const int tid   = threadIdx.x;
    const int lane  = tid & 63;
    const int kt    = tid >> 6;                // wave = k-tile 0..3
    const int row16 = lane & 15;
    const int kg    = lane >> 4;               // 0..3
    const int b0    = bq * 128;

    // h fragments (B-operand): 8 m-tiles of 16 rows.
    short8v hfr[8];
#pragma unroll
    for (int mt = 0; mt < 8; ++mt)
        hfr[mt] = *reinterpret_cast<const short8v*>(
            hbf + (b0 + mt * 16 + row16) * H_SZ + kg * 8);

    // lw fragments (A-operand) for 20 consecutive genes, loaded once.
    const int g0 = chunk * GPC;
    short8v afr[GPC];
#pragma unroll
    for (int gi = 0; gi < GPC; ++gi) {
        const size_t gene = (size_t)genes[g0 + gi];
        const float* ap = lw + gene * (size_t)(H_SZ * K_SZ)
                             + (size_t)(kg * 8) * K_SZ + kt * 16 + row16;
#pragma unroll
        for (int j = 0; j < 8; ++j)
            afr[gi][j] = (short)f2bf(ap[(size_t)j * K_SZ]);
    }

    const size_t GK = (size_t)G_OI_N * K_SZ;
    for (int mt = 0; mt < 8; ++mt) {
#pragma unroll
        for (int half = 0; half < 2; ++half) {
            // compute 10 genes -> LDS tile [row16][g][k(pad 68)]
#pragma unroll
            for (int gi = 0; gi < 10; ++gi) {
                float4v acc = {0.f, 0.f, 0.f, 0.f};
                acc = __builtin_amdgcn_mfma_f32_16x16x32_bf16(
                          afr[half * 10 + gi], hfr[mt], acc, 0, 0, 0);
                *reinterpret_cast<float4v*>(
                    lt + row16 * (10 * KPAD) + gi * KPAD + kt * 16 + kg * 4) = acc;
            }
            __syncthreads();
            // stream tile out: contiguous per row (10 genes x 256 B = 2.5 KB)
            float* obase = out + (size_t)(g0 + half * 10) * K_SZ
                               + (size_t)(b0 + mt * 16) * GK;
#pragma unroll
            for (int p = 0; p < 10; ++p) {
                const int f   = p * 256 + tid;       // 0..2559
                const int r   = f / 160;             // row 0..15
                const int rem = f - r * 160;
                const int g   = rem >> 4;            // gene 0..9
                const int k4  = rem & 15;            // float4 index in k
                float4v v = *reinterpret_cast<const float4v*>(
                    lt + r * (10 * KPAD) + g * KPAD + k4 * 4);
                *reinterpret_cast<float4v*>(
                    obase + (size_t)r * GK + g * K_SZ + k4 * 4) = v;
            }
            __syncthreads();
        }
    }
}

// ---------------- Kernel C: rho[b,g] = sum_h h[b,h] * rw[genes[g],h]
__global__ __launch_bounds__(256) void rho_kernel(
    const float* __restrict__ hbuf, const int* __restrict__ genes,
    const float* __restrict__ rw, float* __restrict__ out)
{
    const int gx = blockIdx.x % 20;
    const int bx = blockIdx.x / 20;
    const int g = gx * 256 + threadIdx.x;
    if (g >= G_OI_N) return;
    const size_t gene = (size_t)genes[g];

    float rreg[H_SZ];
    const float4* rp = reinterpret_cast<const float4*>(rw + gene * H_SZ);
#pragma unroll
    for (int q = 0; q < 8; ++q) {
        float4 rv = rp[q];
        rreg[4 * q + 0] = rv.x; rreg[4 * q + 1] = rv.y;
        rreg[4 * q + 2] = rv.z; rreg[4 * q + 3] = rv.w;
    }

    const int b0 = bx * 32;
    for (int b = b0; b < b0 + 32; ++b) {
        const float4* hp = reinterpret_cast<const float4*>(hbuf + b * H_SZ);
        float a0 = 0.f, a1 = 0.f, a2 = 0.f, a3 = 0.f;
#pragma unroll
        for (int q = 0; q < 8; ++q) {
            float4 hv = hp[q];
            a0 = fmaf(hv.x, rreg[4 * q + 0], a0);
            a1 = fmaf(hv.y, rreg[4 * q + 1], a1);
            a2 = fmaf(hv.z, rreg[4 * q + 2], a2);
            a3 = fmaf(hv.w, rreg[4 * q + 3], a3);
        }
        out[(size_t)b * G_OI_N + g] = (a0 + a1) + (a2 + a3);
    }
}

extern "C" void kernel_launch(void* const* d_in, const int* in_sizes, int n_in,
                              void* d_out, int out_size, void* d_ws, size_t ws_size,
                              hipStream_t stream)
{
    // Bind inputs by SIZE SIGNATURE (all sizes unique; robust to ordering).
    const float *latent = nullptr, *W1 = nullptr, *lw = nullptr, *rw = nullptr;
    const int* genes = nullptr;
    const float* small[5] = {nullptr, nullptr, nullptr, nullptr, nullptr};
    int nsmall = 0;
    for (int i = 0; i < n_in; ++i) {
        switch (in_sizes[i]) {
            case 32768:    latent = (const float*)d_in[i]; break;
            case 5000:
            case 10000:    genes  = (const int*)d_in[i];   break;
            case 2048:     W1     = (const float*)d_in[i]; break;
            case 40960000: lw     = (const float*)d_in[i]; break;
            case 640000:   rw     = (const float*)d_in[i]; break;
            case 32: if (nsmall < 5) small[nsmall++] = (const float*)d_in[i]; break;
            default: break;
        }
    }
    if (!latent || !genes || !W1 || !lw || !rw || nsmall < 5) return;
    const float* b1v   = small[0];
    const float* gamma = small[1];
    const float* beta  = small[2];
    const float* mean  = small[3];
    const float* var   = small[4];

    float* hbuf = (float*)d_ws;                                    // 64 KB fp32 h
    unsigned short* hbf = (unsigned short*)((char*)d_ws + 65536);  // 32 KB bf16 h
    float* logit_out = (float*)d_out;                              // [512,5000,64]
    float* rho_out   = logit_out + (size_t)B_SZ * G_OI_N * K_SZ;   // [512,5000]

    mlp_kernel<<<(B_SZ * H_SZ) / 256, 256, 0, stream>>>(latent, W1, b1v, gamma, beta,
                                                        mean, var, hbuf, hbf);
    logit_kernel<<<4 * NCHUNK, 256, 0, stream>>>(hbf, genes, lw, logit_out);
    rho_kernel<<<20 * 16, 256, 0, stream>>>(hbuf, genes, rw, rho_out);
}